// Round 1
// baseline (123.085 us; speedup 1.0000x reference)
//
#include <hip/hip_runtime.h>
#include <math.h>

#define NF 300
#define NC 75     // float4 chunks per row
#define ROWS 32   // rows per block (256 threads / 8 lanes-per-row)
#define G 8       // lanes cooperating on one row
#define CPL 10    // float4 chunks owned per lane (lane 7: 5)

// 7-tap conv producing blur for the 4 elements of chunk A.
// carries c0..c2 = raw[4m-3..4m-1], A = chunk m, B = chunk m+1 (only .x/.y/.z used)
#define CONV(b0,b1,b2,b3,c0,c1,c2,A,B) \
    b0 = kk[0]*c0;  b0=fmaf(kk[1],c1 ,b0); b0=fmaf(kk[2],c2 ,b0); b0=fmaf(kk[3],A.x,b0); b0=fmaf(kk[4],A.y,b0); b0=fmaf(kk[5],A.z,b0); b0=fmaf(kk[6],A.w,b0); \
    b1 = kk[0]*c1;  b1=fmaf(kk[1],c2 ,b1); b1=fmaf(kk[2],A.x,b1); b1=fmaf(kk[3],A.y,b1); b1=fmaf(kk[4],A.z,b1); b1=fmaf(kk[5],A.w,b1); b1=fmaf(kk[6],B.x,b1); \
    b2 = kk[0]*c2;  b2=fmaf(kk[1],A.x,b2); b2=fmaf(kk[2],A.y,b2); b2=fmaf(kk[3],A.z,b2); b2=fmaf(kk[4],A.w,b2); b2=fmaf(kk[5],B.x,b2); b2=fmaf(kk[6],B.y,b2); \
    b3 = kk[0]*A.x; b3=fmaf(kk[1],A.y,b3); b3=fmaf(kk[2],A.z,b3); b3=fmaf(kk[3],A.w,b3); b3=fmaf(kk[4],B.x,b3); b3=fmaf(kk[5],B.y,b3); b3=fmaf(kk[6],B.z,b3);

__global__ __launch_bounds__(256) void peak_mover_loss_kernel(
    const float* __restrict__ in,     // (B, 300)
    const float* __restrict__ freqs,  // (300,) unused: freqs[j] = j*2/299 - 1
    const float* __restrict__ kw,     // (7,)
    float* __restrict__ out)          // (B,)
{
    __shared__ __align__(16) float lds[ROWS * NF];   // 38400 B -> 4 blocks/CU

    const int tid = threadIdx.x;
    const int rowBase = blockIdx.x * ROWS;

    // ---- stage 32 contiguous rows, perfectly coalesced (2400 float4) ----
    {
        const float4* gin = reinterpret_cast<const float4*>(in + (size_t)rowBase * NF);
        float4* l4 = reinterpret_cast<float4*>(lds);
#pragma unroll
        for (int i = 0; i < 10; ++i) {
            const int idx = tid + 256 * i;
            if (idx < ROWS * NC) l4[idx] = gin[idx];
        }
    }

    float kk[7];
#pragma unroll
    for (int t = 0; t < 7; ++t) kk[t] = kw[t];   // uniform -> scalar loads

    __syncthreads();

    const int g = tid >> 3;                      // row within block (0..31)
    const int l = tid & 7;                       // lane within row group (0..7)
    const float4* rp4 = reinterpret_cast<const float4*>(lds + g * NF);

    const int cs = CPL * l;                      // first owned chunk
    const int nc = (l == G - 1) ? (NC - cs) : CPL;  // lane 7 owns 5 chunks

    // ---- pass 1: blur + peak flags over owned j in [40l-1, 40l+4*nc-2] ----
    // prologue: carries + blur halo (prev1=blur[40l-1], prev2=blur[40l-2])
    float c0, c1, c2, prev1, prev2;
    if (l == 0) {
        c0 = c1 = c2 = 0.f; prev1 = prev2 = -INFINITY;
    } else {
        const float4 P = rp4[cs - 2];
        const float4 Q = rp4[cs - 1];
        const float4 Rv = rp4[cs];
        float pb0, pb1, pb2, pb3;
        float pc0 = P.y, pc1 = P.z, pc2 = P.w;
        CONV(pb0, pb1, pb2, pb3, pc0, pc1, pc2, Q, Rv);
        (void)pb0; (void)pb1;
        prev2 = pb2; prev1 = pb3;
        c0 = Q.y; c1 = Q.z; c2 = Q.w;
    }

    int cnt = 0, p0 = 0, p1 = 0;
    float4 A = rp4[cs];
    for (int t = 0; t < nc; ++t) {
        const int m = cs + t;
        float4 B = make_float4(0.f, 0.f, 0.f, 0.f);
        if (m + 1 < NC) B = rp4[m + 1];
        float b0, b1, b2, b3;
        CONV(b0, b1, b2, b3, c0, c1, c2, A, B);
        const int base = 4 * m;
        if (prev1 > prev2 && prev1 > b0) { if (cnt==0) p0=base-1; else if (cnt==1) p1=base-1; ++cnt; }
        if (b0 > prev1 && b0 > b1)       { if (cnt==0) p0=base;   else if (cnt==1) p1=base;   ++cnt; }
        if (b1 > b0 && b1 > b2)          { if (cnt==0) p0=base+1; else if (cnt==1) p1=base+1; ++cnt; }
        if (b2 > b1 && b2 > b3)          { if (cnt==0) p0=base+2; else if (cnt==1) p1=base+2; ++cnt; }
        prev2 = b2; prev1 = b3;
        c0 = A.y; c1 = A.z; c2 = A.w;
        A = B;
    }
    // right boundary j=299 (lane 7 only): peak iff blur[299] > blur[298]
    if (l == G - 1 && prev1 > prev2) { if (cnt==0) p0=NF-1; else if (cnt==1) p1=NF-1; ++cnt; }

    // ---- ordered merge of (cnt,p0,p1) across the 8 lanes of the group ----
#pragma unroll
    for (int o = 1; o < G; o <<= 1) {
        const int oc = __shfl_xor(cnt, o, G);
        const int q0 = __shfl_xor(p0, o, G);
        const int q1 = __shfl_xor(p1, o, G);
        const bool right = (l & o) != 0;        // partner owns the lower index range
        const int Lc = right ? oc : cnt, Rc = right ? cnt : oc;
        const int L0 = right ? q0 : p0,  R0 = right ? p0 : q0;
        const int L1 = right ? q1 : p1,  R1 = right ? p1 : q1;
        p0 = (Lc >= 1) ? L0 : R0;
        p1 = (Lc >= 2) ? L1 : ((Lc == 1) ? R0 : R1);
        cnt = min(Lc + Rc, 2);
    }
    const int end = (cnt >= 2) ? ((p0 + p1) >> 1) : (NF - 1);   // end >= 1 always

    // ---- pass 2: softmax-argmax over owned j < end (LDS-hot recompute) ----
    const float fsc = 2.0f / 299.0f;
    float s = 0.f, tt = 0.f;
    if (4 * cs < end) {
        float d0, d1, d2;
        if (l == 0) { d0 = d1 = d2 = 0.f; }
        else { const float4 Q = rp4[cs - 1]; d0 = Q.y; d1 = Q.z; d2 = Q.w; }
        float4 A2 = rp4[cs];
        for (int t = 0; t < nc; ++t) {
            const int m = cs + t;
            const int base = 4 * m;
            if (base >= end) break;
            float4 B = make_float4(0.f, 0.f, 0.f, 0.f);
            if (m + 1 < NC) B = rp4[m + 1];
            float b0, b1, b2, b3;
            CONV(b0, b1, b2, b3, d0, d1, d2, A2, B);
            if (base     < end) { float e=__expf(b0); s+=e; tt=fmaf(e, fmaf((float)(base  ), fsc, -1.f), tt); }
            if (base + 1 < end) { float e=__expf(b1); s+=e; tt=fmaf(e, fmaf((float)(base+1), fsc, -1.f), tt); }
            if (base + 2 < end) { float e=__expf(b2); s+=e; tt=fmaf(e, fmaf((float)(base+2), fsc, -1.f), tt); }
            if (base + 3 < end) { float e=__expf(b3); s+=e; tt=fmaf(e, fmaf((float)(base+3), fsc, -1.f), tt); }
            d0 = A2.y; d1 = A2.z; d2 = A2.w;
            A2 = B;
        }
    }
#pragma unroll
    for (int o = 1; o < G; o <<= 1) {
        s  += __shfl_xor(s,  o, G);
        tt += __shfl_xor(tt, o, G);
    }
    if (l == 0) out[rowBase + g] = -(tt / s);
}

extern "C" void kernel_launch(void* const* d_in, const int* in_sizes, int n_in,
                              void* d_out, int out_size, void* d_ws, size_t ws_size,
                              hipStream_t stream) {
    const float* fr    = (const float*)d_in[0];
    const float* freqs = (const float*)d_in[1];
    const float* kw    = (const float*)d_in[2];
    float* outp = (float*)d_out;

    const int nrows = in_sizes[0] / NF;          // 65536
    const int block = 256;
    const int grid  = nrows / ROWS;              // 2048
    peak_mover_loss_kernel<<<grid, block, 0, stream>>>(fr, freqs, kw, outp);
}

// Round 2
// 114.628 us; speedup vs baseline: 1.0738x; 1.0738x over previous
//
#include <hip/hip_runtime.h>
#include <math.h>

#define NF 300
#define NC 75      // float4 chunks per row
#define G 4        // lanes cooperating per row
#define CPW 5      // chunks owned per lane per window
#define WCH (G*CPW) // 20 chunks = 80 floats per window
#define NW 4       // windows covering 75 chunks

// 7-tap conv producing blur for the 4 elements of chunk A.
// carries c0..c2 = raw[4m-3..4m-1], A = chunk m, B = chunk m+1 (only .x/.y/.z used)
#define CONV(b0,b1,b2,b3,c0,c1,c2,A,B) \
    b0 = kk[0]*c0;  b0=fmaf(kk[1],c1 ,b0); b0=fmaf(kk[2],c2 ,b0); b0=fmaf(kk[3],A.x,b0); b0=fmaf(kk[4],A.y,b0); b0=fmaf(kk[5],A.z,b0); b0=fmaf(kk[6],A.w,b0); \
    b1 = kk[0]*c1;  b1=fmaf(kk[1],c2 ,b1); b1=fmaf(kk[2],A.x,b1); b1=fmaf(kk[3],A.y,b1); b1=fmaf(kk[4],A.z,b1); b1=fmaf(kk[5],A.w,b1); b1=fmaf(kk[6],B.x,b1); \
    b2 = kk[0]*c2;  b2=fmaf(kk[1],A.x,b2); b2=fmaf(kk[2],A.y,b2); b2=fmaf(kk[3],A.z,b2); b2=fmaf(kk[4],A.w,b2); b2=fmaf(kk[5],B.x,b2); b2=fmaf(kk[6],B.y,b2); \
    b3 = kk[0]*A.x; b3=fmaf(kk[1],A.y,b3); b3=fmaf(kk[2],A.z,b3); b3=fmaf(kk[3],A.w,b3); b3=fmaf(kk[4],B.x,b3); b3=fmaf(kk[5],B.y,b3); b3=fmaf(kk[6],B.z,b3);

__global__ __launch_bounds__(256) void peak_mover_loss_kernel(
    const float* __restrict__ in,     // (B, 300)
    const float* __restrict__ freqs,  // (300,) unused: freqs[j] = j*2/299 - 1
    const float* __restrict__ kw,     // (7,)
    float* __restrict__ out)          // (B,)
{
    const int tid = threadIdx.x;
    const int l   = tid & (G - 1);                    // lane in row-group (0..3)
    const int row = blockIdx.x * (256 / G) + (tid >> 2);
    const float4* rp4 = reinterpret_cast<const float4*>(in + (size_t)row * NF);

    float kk[7];
#pragma unroll
    for (int t = 0; t < 7; ++t) kk[t] = kw[t];        // uniform -> scalar loads

    // blur values of the most recent window's owned chunks (static indexing only)
    float bl[CPW][4];
    int Cnt = 0, P0 = 0, P1 = 0;                      // running first-two-peaks
    int wexit = NW;                                   // window where we found 2 peaks

    // ================= pass 1: windowed scan, group-level early exit ==========
#pragma unroll 1
    for (int w = 0; w < NW; ++w) {
        const int cs = WCH * w + CPW * l;             // first owned chunk
        const int nc = (cs < NC) ? ((NC - cs < CPW) ? (NC - cs) : CPW) : 0;
        int cnt = 0, p0 = 0, p1 = 0;

        if (nc > 0) {
            // prefetch owned chunks + right boundary chunk (issued back-to-back)
            float4 ch[CPW + 1];
#pragma unroll
            for (int t = 0; t <= CPW; ++t) {
                float4 v = make_float4(0.f, 0.f, 0.f, 0.f);
                if (t <= nc && cs + t < NC) v = rp4[cs + t];
                ch[t] = v;
            }

            // halo: carries + blur[4cs-2], blur[4cs-1]
            float c0, c1, c2, prev1, prev2;
            if (cs == 0) {
                c0 = c1 = c2 = 0.f; prev1 = prev2 = -INFINITY;
            } else {
                const float4 P = rp4[cs - 2];
                const float4 Q = rp4[cs - 1];
                float pb0, pb1, pb2, pb3;
                float pc0 = P.y, pc1 = P.z, pc2 = P.w;
                CONV(pb0, pb1, pb2, pb3, pc0, pc1, pc2, Q, ch[0]);
                (void)pb0; (void)pb1;
                prev2 = pb2; prev1 = pb3;
                c0 = Q.y; c1 = Q.z; c2 = Q.w;
            }

#pragma unroll
            for (int t = 0; t < CPW; ++t) {
                if (t < nc) {
                    float b0, b1, b2, b3;
                    CONV(b0, b1, b2, b3, c0, c1, c2, ch[t], ch[t + 1]);
                    bl[t][0] = b0; bl[t][1] = b1; bl[t][2] = b2; bl[t][3] = b3;
                    const int base = 4 * (cs + t);
                    if (prev1 > prev2 && prev1 > b0) { if (cnt==0) p0=base-1; else if (cnt==1) p1=base-1; ++cnt; }
                    if (b0 > prev1 && b0 > b1)       { if (cnt==0) p0=base;   else if (cnt==1) p1=base;   ++cnt; }
                    if (b1 > b0 && b1 > b2)          { if (cnt==0) p0=base+1; else if (cnt==1) p1=base+1; ++cnt; }
                    if (b2 > b1 && b2 > b3)          { if (cnt==0) p0=base+2; else if (cnt==1) p1=base+2; ++cnt; }
                    prev2 = b2; prev1 = b3;
                    c0 = ch[t].y; c1 = ch[t].z; c2 = ch[t].w;
                }
            }
            // right boundary j=299: owned by the lane holding the final chunk
            if (cs + nc == NC && prev1 > prev2) { if (cnt==0) p0=NF-1; else if (cnt==1) p1=NF-1; ++cnt; }
        }

        // ---- ordered merge of (cnt,p0,p1) across the 4 lanes of the group ----
#pragma unroll
        for (int o = 1; o < G; o <<= 1) {
            const int oc = __shfl_xor(cnt, o, G);
            const int q0 = __shfl_xor(p0, o, G);
            const int q1 = __shfl_xor(p1, o, G);
            const bool right = (l & o) != 0;          // partner owns lower indices
            const int Lc = right ? oc : cnt, Rc = right ? cnt : oc;
            const int L0 = right ? q0 : p0,  R0 = right ? p0 : q0;
            const int L1 = right ? q1 : p1,  R1 = right ? p1 : q1;
            p0 = (Lc >= 1) ? L0 : R0;
            p1 = (Lc >= 2) ? L1 : ((Lc == 1) ? R0 : R1);
            cnt = (Lc + Rc < 2) ? (Lc + Rc) : 2;
        }
        // append this window's peaks after the running ones (index order holds)
        if (Cnt == 0)      { P0 = p0; P1 = p1; Cnt = cnt; }
        else if (Cnt == 1) { if (cnt >= 1) { P1 = p0; Cnt = 2; } }
        if (Cnt >= 2) { wexit = w; break; }
    }

    const int end = (Cnt >= 2) ? ((P0 + P1) >> 1) : (NF - 1);   // end >= 1 always

    // ================= pass 2: softmax-argmax over j < end ====================
    const float fsc = 2.0f / 299.0f;
    float s = 0.f, tt = 0.f;

    if (wexit == 0) {
        // common case: end <= 79, all needed blur values live in registers
        const int jb = 4 * CPW * l;                   // 20*l
#pragma unroll
        for (int t = 0; t < CPW; ++t) {
#pragma unroll
            for (int e = 0; e < 4; ++e) {
                const int j = jb + 4 * t + e;
                if (j < end) {
                    const float ev = __expf(bl[t][e]);
                    s += ev;
                    tt = fmaf(ev, fmaf((float)j, fsc, -1.f), tt);
                }
            }
        }
    } else {
        // rare: recompute from global (L1/L2-hot from pass 1)
#pragma unroll 1
        for (int w2 = 0; w2 * (4 * WCH) < end; ++w2) {
            const int cs2 = WCH * w2 + CPW * l;
            if (cs2 < NC && 4 * cs2 < end) {
                float d0, d1, d2;
                if (cs2 == 0) { d0 = d1 = d2 = 0.f; }
                else { const float4 Q = rp4[cs2 - 1]; d0 = Q.y; d1 = Q.z; d2 = Q.w; }
                float4 A2 = rp4[cs2];
#pragma unroll 1
                for (int t = 0; t < CPW; ++t) {
                    const int m = cs2 + t;
                    const int base = 4 * m;
                    if (m >= NC || base >= end) break;
                    float4 Bv = make_float4(0.f, 0.f, 0.f, 0.f);
                    if (m + 1 < NC) Bv = rp4[m + 1];
                    float b0, b1, b2, b3;
                    CONV(b0, b1, b2, b3, d0, d1, d2, A2, Bv);
                    if (base     < end) { float e=__expf(b0); s+=e; tt=fmaf(e, fmaf((float)(base  ), fsc, -1.f), tt); }
                    if (base + 1 < end) { float e=__expf(b1); s+=e; tt=fmaf(e, fmaf((float)(base+1), fsc, -1.f), tt); }
                    if (base + 2 < end) { float e=__expf(b2); s+=e; tt=fmaf(e, fmaf((float)(base+2), fsc, -1.f), tt); }
                    if (base + 3 < end) { float e=__expf(b3); s+=e; tt=fmaf(e, fmaf((float)(base+3), fsc, -1.f), tt); }
                    d0 = A2.y; d1 = A2.z; d2 = A2.w;
                    A2 = Bv;
                }
            }
        }
    }

    // reduce softmax partials across the 4 lanes
#pragma unroll
    for (int o = 1; o < G; o <<= 1) {
        s  += __shfl_xor(s,  o, G);
        tt += __shfl_xor(tt, o, G);
    }
    if (l == 0) out[row] = -(tt / s);
}

extern "C" void kernel_launch(void* const* d_in, const int* in_sizes, int n_in,
                              void* d_out, int out_size, void* d_ws, size_t ws_size,
                              hipStream_t stream) {
    const float* fr    = (const float*)d_in[0];
    const float* freqs = (const float*)d_in[1];
    const float* kw    = (const float*)d_in[2];
    float* outp = (float*)d_out;

    const int nrows = in_sizes[0] / NF;               // 65536
    const int block = 256;
    const int grid  = (nrows * G) / block;            // 1024
    peak_mover_loss_kernel<<<grid, block, 0, stream>>>(fr, freqs, kw, outp);
}

// Round 3
// 107.594 us; speedup vs baseline: 1.1440x; 1.0654x over previous
//
#include <hip/hip_runtime.h>
#include <math.h>

#define NF 300
#define NC 75      // float4 chunks per row

// 7-tap conv producing blur for the 4 elements of chunk A.
// carries c0..c2 = raw[4m-3..4m-1], A = chunk m, B = chunk m+1 (only .x/.y/.z used)
#define CONV(b0,b1,b2,b3,c0,c1,c2,A,B) \
    b0 = kk[0]*c0;  b0=fmaf(kk[1],c1 ,b0); b0=fmaf(kk[2],c2 ,b0); b0=fmaf(kk[3],A.x,b0); b0=fmaf(kk[4],A.y,b0); b0=fmaf(kk[5],A.z,b0); b0=fmaf(kk[6],A.w,b0); \
    b1 = kk[0]*c1;  b1=fmaf(kk[1],c2 ,b1); b1=fmaf(kk[2],A.x,b1); b1=fmaf(kk[3],A.y,b1); b1=fmaf(kk[4],A.z,b1); b1=fmaf(kk[5],A.w,b1); b1=fmaf(kk[6],B.x,b1); \
    b2 = kk[0]*c2;  b2=fmaf(kk[1],A.x,b2); b2=fmaf(kk[2],A.y,b2); b2=fmaf(kk[3],A.z,b2); b2=fmaf(kk[4],A.w,b2); b2=fmaf(kk[5],B.x,b2); b2=fmaf(kk[6],B.y,b2); \
    b3 = kk[0]*A.x; b3=fmaf(kk[1],A.y,b3); b3=fmaf(kk[2],A.z,b3); b3=fmaf(kk[3],A.w,b3); b3=fmaf(kk[4],B.x,b3); b3=fmaf(kk[5],B.y,b3); b3=fmaf(kk[6],B.z,b3);

#define PKCHK(J,V) { if (cnt==0) p0=(J); else if (cnt==1) p1=(J); ++cnt; (void)(V); }

__global__ __launch_bounds__(256) void peak_mover_loss_kernel(
    const float* __restrict__ in,     // (B, 300)
    const float* __restrict__ freqs,  // (300,) unused: freqs[j] = j*2/299 - 1
    const float* __restrict__ kw,     // (7,)
    float* __restrict__ out)          // (B,)
{
    const int row = blockIdx.x * blockDim.x + threadIdx.x;
    const float4* rp4 = reinterpret_cast<const float4*>(in + (size_t)row * NF);

    float kk[7];
#pragma unroll
    for (int t = 0; t < 7; ++t) kk[t] = kw[t];   // uniform -> scalar loads

    // ---- batch 1: chunks 0..7 in ONE round-trip (8 back-to-back dwordx4) ----
    float4 ch[8];
#pragma unroll
    for (int t = 0; t < 8; ++t) ch[t] = rp4[t];

    // blur[0..27] fully in registers; peak checks j = 0..26
    float bl[28];
    float c0 = 0.f, c1 = 0.f, c2 = 0.f;
    float prev1 = -INFINITY, prev2 = -INFINITY;
    int cnt = 0, p0 = 0, p1 = 0;
#pragma unroll
    for (int m = 0; m < 7; ++m) {
        float b0, b1, b2, b3;
        CONV(b0, b1, b2, b3, c0, c1, c2, ch[m], ch[m + 1]);
        bl[4*m] = b0; bl[4*m+1] = b1; bl[4*m+2] = b2; bl[4*m+3] = b3;
        const int base = 4 * m;
        if (prev1 > prev2 && prev1 > b0) PKCHK(base - 1, 0)
        if (b0 > prev1 && b0 > b1)       PKCHK(base,     0)
        if (b1 > b0 && b1 > b2)          PKCHK(base + 1, 0)
        if (b2 > b1 && b2 > b3)          PKCHK(base + 2, 0)
        prev2 = b2; prev1 = b3;
        c0 = ch[m].y; c1 = ch[m].z; c2 = ch[m].w;
    }
    // state: carries = ch[6].yzw, A4 = ch[7], prev1 = blur[27], prev2 = blur[26]
    float4 A4 = ch[7];

    // ---- continuation: straggler lanes only, 16 chunks (64 samples) per trip ----
    int mc = 7;                               // next chunk to convolve
#pragma unroll 1
    while (cnt < 2 && mc < NC) {
        float4 cc[17];
        cc[0] = A4;
#pragma unroll
        for (int t = 1; t <= 16; ++t) {
            const int idx = mc + t;
            float4 v = make_float4(0.f, 0.f, 0.f, 0.f);
            if (idx < NC) v = rp4[idx];       // exec-masked: done lanes load nothing
            cc[t] = v;
        }
#pragma unroll
        for (int t = 0; t < 16; ++t) {
            const int m = mc + t;
            if (m < NC && cnt < 2) {
                float b0, b1, b2, b3;
                CONV(b0, b1, b2, b3, c0, c1, c2, cc[t], cc[t + 1]);
                const int base = 4 * m;
                if (prev1 > prev2 && prev1 > b0) PKCHK(base - 1, 0)
                if (b0 > prev1 && b0 > b1)       PKCHK(base,     0)
                if (b1 > b0 && b1 > b2)          PKCHK(base + 1, 0)
                if (b2 > b1 && b2 > b3)          PKCHK(base + 2, 0)
                if (m == NC - 1 && cnt < 2 && b3 > b2) PKCHK(NF - 1, 0)
                prev2 = b2; prev1 = b3;
                c0 = cc[t].y; c1 = cc[t].z; c2 = cc[t].w;
            }
        }
        A4 = cc[16];
        mc += 16;
    }

    const int end = (cnt >= 2) ? ((p0 + p1) >> 1) : (NF - 1);   // end >= 1 always

    // ---- pass 2: softmax-argmax over j < end ----
    const float fsc = 2.0f / 299.0f;
    float s = 0.f, tt = 0.f;
    if (end <= 28) {
        // common case: all needed blur values already in registers
#pragma unroll
        for (int j = 0; j < 28; ++j) {
            if (j < end) {
                const float e = __expf(bl[j]);
                s += e;
                tt = fmaf(e, fmaf((float)j, fsc, -1.f), tt);
            }
        }
    } else {
        // rare: streaming recompute (lines are L1/L2-hot from pass 1)
        float d0 = 0.f, d1 = 0.f, d2 = 0.f;
        float4 A = rp4[0], B = rp4[1], C = rp4[2], D = rp4[3];
        int m = 0;
#pragma unroll 1
        while (4 * m < end) {
            float b0, b1, b2, b3;
            CONV(b0, b1, b2, b3, d0, d1, d2, A, B);
            const int base = 4 * m;
            if (base     < end) { float e=__expf(b0); s+=e; tt=fmaf(e, fmaf((float)(base  ), fsc, -1.f), tt); }
            if (base + 1 < end) { float e=__expf(b1); s+=e; tt=fmaf(e, fmaf((float)(base+1), fsc, -1.f), tt); }
            if (base + 2 < end) { float e=__expf(b2); s+=e; tt=fmaf(e, fmaf((float)(base+2), fsc, -1.f), tt); }
            if (base + 3 < end) { float e=__expf(b3); s+=e; tt=fmaf(e, fmaf((float)(base+3), fsc, -1.f), tt); }
            d0 = A.y; d1 = A.z; d2 = A.w;
            A = B; B = C; C = D;
            const int k = m + 4;
            float4 nd = make_float4(0.f, 0.f, 0.f, 0.f);
            if (k < NC) nd = rp4[k];
            D = nd;
            ++m;
        }
    }

    out[row] = -(tt / s);
}

extern "C" void kernel_launch(void* const* d_in, const int* in_sizes, int n_in,
                              void* d_out, int out_size, void* d_ws, size_t ws_size,
                              hipStream_t stream) {
    const float* fr    = (const float*)d_in[0];
    const float* freqs = (const float*)d_in[1];
    const float* kw    = (const float*)d_in[2];
    float* outp = (float*)d_out;

    const int nrows = in_sizes[0] / NF;          // 65536
    const int block = 256;
    const int grid  = nrows / block;             // 256
    peak_mover_loss_kernel<<<grid, block, 0, stream>>>(fr, freqs, kw, outp);
}

// Round 4
// 105.616 us; speedup vs baseline: 1.1654x; 1.0187x over previous
//
#include <hip/hip_runtime.h>
#include <math.h>

#define NF 300
#define NC 75      // float4 chunks per row
#define CH 14      // chunks loaded in batch 1 (224 B/row)
#define BL (4*CH-4) // 52 blur values held in registers (j = 0..51)
// peak checks covered in batch 1: j <= 4*CH-6 = 50

// 7-tap conv producing blur for the 4 elements of chunk A.
// carries c0..c2 = raw[4m-3..4m-1], A = chunk m, B = chunk m+1 (only .x/.y/.z used)
#define CONV(b0,b1,b2,b3,c0,c1,c2,A,B) \
    b0 = kk[0]*c0;  b0=fmaf(kk[1],c1 ,b0); b0=fmaf(kk[2],c2 ,b0); b0=fmaf(kk[3],A.x,b0); b0=fmaf(kk[4],A.y,b0); b0=fmaf(kk[5],A.z,b0); b0=fmaf(kk[6],A.w,b0); \
    b1 = kk[0]*c1;  b1=fmaf(kk[1],c2 ,b1); b1=fmaf(kk[2],A.x,b1); b1=fmaf(kk[3],A.y,b1); b1=fmaf(kk[4],A.z,b1); b1=fmaf(kk[5],A.w,b1); b1=fmaf(kk[6],B.x,b1); \
    b2 = kk[0]*c2;  b2=fmaf(kk[1],A.x,b2); b2=fmaf(kk[2],A.y,b2); b2=fmaf(kk[3],A.z,b2); b2=fmaf(kk[4],A.w,b2); b2=fmaf(kk[5],B.x,b2); b2=fmaf(kk[6],B.y,b2); \
    b3 = kk[0]*A.x; b3=fmaf(kk[1],A.y,b3); b3=fmaf(kk[2],A.z,b3); b3=fmaf(kk[3],A.w,b3); b3=fmaf(kk[4],B.x,b3); b3=fmaf(kk[5],B.y,b3); b3=fmaf(kk[6],B.z,b3);

#define PKCHK(J) { if (cnt==0) p0=(J); else if (cnt==1) p1=(J); ++cnt; }

__global__ __launch_bounds__(256, 1) void peak_mover_loss_kernel(
    const float* __restrict__ in,     // (B, 300)
    const float* __restrict__ freqs,  // (300,) unused: freqs[j] = j*2/299 - 1
    const float* __restrict__ kw,     // (7,)
    float* __restrict__ out)          // (B,)
{
    const int row = blockIdx.x * blockDim.x + threadIdx.x;
    const float4* rp4 = reinterpret_cast<const float4*>(in + (size_t)row * NF);
    (void)freqs;

    // ---- batch 1: chunks 0..13 in ONE round-trip (14 back-to-back dwordx4) ----
    float4 ch[CH];
#pragma unroll
    for (int t = 0; t < CH; ++t) ch[t] = rp4[t];

    float kk[7];
#pragma unroll
    for (int t = 0; t < 7; ++t) kk[t] = kw[t];   // uniform -> scalar loads

    // blur[0..51] fully in registers; peak checks j = 0..50
    float bl[BL];
    float c0 = 0.f, c1 = 0.f, c2 = 0.f;
    float prev1 = -INFINITY, prev2 = -INFINITY;
    int cnt = 0, p0 = 0, p1 = 0;
#pragma unroll
    for (int m = 0; m < CH - 1; ++m) {
        // wave-uniform early exit: every lane's end < its p1 <= last checked j,
        // so bl[] beyond the break point is never consumed.
        if (m >= 2 && (m & 1) == 0) { if (__all(cnt >= 2)) break; }
        float b0, b1, b2, b3;
        CONV(b0, b1, b2, b3, c0, c1, c2, ch[m], ch[m + 1]);
        bl[4*m] = b0; bl[4*m+1] = b1; bl[4*m+2] = b2; bl[4*m+3] = b3;
        const int base = 4 * m;
        if (prev1 > prev2 && prev1 > b0) PKCHK(base - 1)
        if (b0 > prev1 && b0 > b1)       PKCHK(base)
        if (b1 > b0 && b1 > b2)          PKCHK(base + 1)
        if (b2 > b1 && b2 > b3)          PKCHK(base + 2)
        prev2 = b2; prev1 = b3;
        c0 = ch[m].y; c1 = ch[m].z; c2 = ch[m].w;
    }
    // (if loop completed) state: carries = ch[12].yzw, prev1 = blur[51]
    float4 A4 = ch[CH - 1];

    // ---- continuation: straggler lanes only (rare), 16 chunks per round-trip ----
    int mc = CH - 1;                          // next chunk to convolve
#pragma unroll 1
    while (cnt < 2 && mc < NC) {              // per-lane: done lanes masked out
        float4 cc[17];
        cc[0] = A4;
#pragma unroll
        for (int t = 1; t <= 16; ++t) {
            const int idx = mc + t;
            float4 v = make_float4(0.f, 0.f, 0.f, 0.f);
            if (idx < NC) v = rp4[idx];       // exec-masked: only stragglers fetch
            cc[t] = v;
        }
#pragma unroll
        for (int t = 0; t < 16; ++t) {
            const int m = mc + t;
            if (m < NC && cnt < 2) {
                float b0, b1, b2, b3;
                CONV(b0, b1, b2, b3, c0, c1, c2, cc[t], cc[t + 1]);
                const int base = 4 * m;
                if (prev1 > prev2 && prev1 > b0) PKCHK(base - 1)
                if (b0 > prev1 && b0 > b1)       PKCHK(base)
                if (b1 > b0 && b1 > b2)          PKCHK(base + 1)
                if (b2 > b1 && b2 > b3)          PKCHK(base + 2)
                if (m == NC - 1 && cnt < 2 && b3 > b2) PKCHK(NF - 1)
                prev2 = b2; prev1 = b3;
                c0 = cc[t].y; c1 = cc[t].z; c2 = cc[t].w;
            }
        }
        A4 = cc[16];
        mc += 16;
    }

    const int end = (cnt >= 2) ? ((p0 + p1) >> 1) : (NF - 1);   // end >= 1 always

    // ---- pass 2: softmax-argmax over j < end ----
    const float fsc = 2.0f / 299.0f;
    float s = 0.f, tt = 0.f;
    if (end <= BL) {
        // common case: all needed blur values already in registers;
        // wave-uniform break once all active lanes are past their end.
#pragma unroll
        for (int jb = 0; jb < BL; jb += 4) {
            if (!__any(jb < end)) break;
#pragma unroll
            for (int e = 0; e < 4; ++e) {
                const int j = jb + e;
                if (j < end) {
                    const float ev = __expf(bl[j]);
                    s += ev;
                    tt = fmaf(ev, fmaf((float)j, fsc, -1.f), tt);
                }
            }
        }
    } else {
        // rare: streaming recompute (lines are L1/L2-hot from pass 1)
        float d0 = 0.f, d1 = 0.f, d2 = 0.f;
        float4 A = rp4[0], B = rp4[1], C = rp4[2], D = rp4[3];
        int m = 0;
#pragma unroll 1
        while (4 * m < end) {
            float b0, b1, b2, b3;
            CONV(b0, b1, b2, b3, d0, d1, d2, A, B);
            const int base = 4 * m;
            if (base     < end) { float e=__expf(b0); s+=e; tt=fmaf(e, fmaf((float)(base  ), fsc, -1.f), tt); }
            if (base + 1 < end) { float e=__expf(b1); s+=e; tt=fmaf(e, fmaf((float)(base+1), fsc, -1.f), tt); }
            if (base + 2 < end) { float e=__expf(b2); s+=e; tt=fmaf(e, fmaf((float)(base+2), fsc, -1.f), tt); }
            if (base + 3 < end) { float e=__expf(b3); s+=e; tt=fmaf(e, fmaf((float)(base+3), fsc, -1.f), tt); }
            d0 = A.y; d1 = A.z; d2 = A.w;
            A = B; B = C; C = D;
            const int k = m + 4;
            float4 nd = make_float4(0.f, 0.f, 0.f, 0.f);
            if (k < NC) nd = rp4[k];
            D = nd;
            ++m;
        }
    }

    out[row] = -(tt / s);
}

extern "C" void kernel_launch(void* const* d_in, const int* in_sizes, int n_in,
                              void* d_out, int out_size, void* d_ws, size_t ws_size,
                              hipStream_t stream) {
    const float* fr    = (const float*)d_in[0];
    const float* freqs = (const float*)d_in[1];
    const float* kw    = (const float*)d_in[2];
    float* outp = (float*)d_out;

    const int nrows = in_sizes[0] / NF;          // 65536
    const int block = 256;
    const int grid  = nrows / block;             // 256
    peak_mover_loss_kernel<<<grid, block, 0, stream>>>(fr, freqs, kw, outp);
}